// Round 6
// baseline (11069.366 us; speedup 1.0000x reference)
//
#include <hip/hip_runtime.h>
#include <hip/hip_bf16.h>

// ---------------------------------------------------------------------------
// 3-layer original-paper GRU, B=128, T=128, I=512, H={512,1024,2048}.
// Round 6: diagonal pipeline (R5) + rebuilt GEMM inner loop.
//  - Wave tile 64x32 (4 waves/block): LDS fragment reads 96 KB/chunk (was 160).
//  - 3-stage LDS buffering, prefetch depth 2, manual s_waitcnt vmcnt(12) +
//    raw s_barrier (never vmcnt(0) mid-loop) -> LLC latency hidden across
//    chunks instead of paid per chunk (R5's __syncthreads drained vmcnt(0)).
//  - sched_barrier(0) fences around the barrier pin compute vs DMA (WAR:
//    buffer (c+2)%3 == (c-1)%3).
// Structure otherwise R5: tick u = (layer l, t=u-l), zr+n launches per tick,
// h state double-buffered by tick parity, input projection fused in K-stream.
// ---------------------------------------------------------------------------

typedef __attribute__((ext_vector_type(8))) short s16x8;
typedef __attribute__((ext_vector_type(4))) float f32x4;

#define LLDS16(g, s)                                                          \
  __builtin_amdgcn_global_load_lds(                                           \
      (const __attribute__((address_space(1))) void*)(g),                     \
      (__attribute__((address_space(3))) void*)(s), 16, 0, 0)

// s_waitcnt imm (gfx9 encoding): lgkm=0xF (no wait), exp=0x7 (no wait), vmcnt low4.
#define WAITCNT_VM12() __builtin_amdgcn_s_waitcnt(0xF7C)
#define WAITCNT_VM0() __builtin_amdgcn_s_waitcnt(0xF70)

__device__ __forceinline__ unsigned short f2b(float f) {
  unsigned int u = __float_as_uint(f);
  unsigned int r = (u + 0x7FFFu + ((u >> 16) & 1u)) >> 16;
  return (unsigned short)r;
}
__device__ __forceinline__ float sigmoidf_(float x) {
  return 1.0f / (1.0f + __expf(-x));
}
__device__ __forceinline__ float tanhf_(float x) {
  x = fminf(fmaxf(x, -15.0f), 15.0f);
  float e = __expf(-2.0f * x);
  return (1.0f - e) / (1.0f + e);
}

struct DiagP {
  const unsigned short* xb;        // [B,T,I] bf16
  const unsigned short* wihzr[3];  // [2H, inl]
  const unsigned short* whhzr[3];  // [2H, H]
  const unsigned short* wihn[3];   // [H, inl]
  const unsigned short* whhn[3];   // [H, H]
  const float* bias[3];            // [3H]
  float* hf[3][2];
  unsigned short* hb[3][2];
  float* zb[3];
  unsigned short* rh[3];
  const float* mask;  // [B,T]
  float* out;         // [B,3584]
};

// ---- staging (4 waves): A 128x128 (32 KB, 8 issues/wave), B 64x128 (16 KB,
// 4 issues/wave). LDS addr of (r,cg) = r*256B + ((cg^(r&15))*16B).
__device__ __forceinline__ void stageA(const unsigned short* __restrict__ g,
                                       size_t ld, int k0, unsigned short* lds) {
  const int tid = threadIdx.x;
  const int wave = tid >> 6, lane = tid & 63;
#pragma unroll
  for (int j = 0; j < 8; ++j) {
    int s = wave * 8 + j;         // 0..31 (1 KB segments, 4 rows each)
    int r = s * 4 + (lane >> 4);  // 0..127
    int cg = (lane & 15) ^ (r & 15);
    LLDS16(g + (size_t)r * ld + k0 + cg * 8, lds + s * 512);
  }
}
__device__ __forceinline__ void stageB(const unsigned short* __restrict__ g,
                                       size_t ld, int rowbase, int k0,
                                       unsigned short* lds) {
  const int tid = threadIdx.x;
  const int wave = tid >> 6, lane = tid & 63;
#pragma unroll
  for (int j = 0; j < 4; ++j) {
    int s = wave * 4 + j;         // 0..15
    int r = s * 4 + (lane >> 4);  // 0..63
    int cg = (lane & 15) ^ (r & 15);
    LLDS16(g + (size_t)(rowbase + r) * ld + k0 + cg * 8, lds + s * 512);
  }
}

// ---- one BK=128 chunk; wave (wg,wc): rows wg*64+[0,64), cols wc*32+[0,32).
__device__ __forceinline__ void cchunk(const unsigned short* Ab,
                                       const unsigned short* Bb,
                                       f32x4 acc[4][2]) {
  const int tid = threadIdx.x;
  const int wave = tid >> 6, lane = tid & 63;
  const int wg = wave >> 1, wc = wave & 1, quad = lane >> 4, l16 = lane & 15;
#pragma unroll
  for (int ks = 0; ks < 4; ++ks) {
    int kg = ks * 4 + quad;
    s16x8 bv[2], av[4];
#pragma unroll
    for (int ni = 0; ni < 2; ++ni) {
      int r = wc * 32 + ni * 16 + l16;
      bv[ni] = *(const s16x8*)(Bb + (size_t)r * 128 + ((kg ^ (r & 15)) * 8));
    }
#pragma unroll
    for (int mi = 0; mi < 4; ++mi) {
      int r = wg * 64 + mi * 16 + l16;
      av[mi] = *(const s16x8*)(Ab + (size_t)r * 128 + ((kg ^ (r & 15)) * 8));
    }
#pragma unroll
    for (int mi = 0; mi < 4; ++mi)
#pragma unroll
      for (int ni = 0; ni < 2; ++ni)
        acc[mi][ni] = __builtin_amdgcn_mfma_f32_16x16x32_bf16(
            av[mi], bv[ni], acc[mi][ni], 0, 0, 0);
  }
}

// acc += A1@B1^T (c1 chunks) + A2@B2^T (c2 chunks); B rows at rowbase.
// 3-stage pipeline, 12 global_load_lds per wave per chunk.
__device__ __forceinline__ void gemm_diag(
    const unsigned short* __restrict__ A1, size_t ldA1, int c1,
    const unsigned short* __restrict__ A2, size_t ldA2, int c2,
    const unsigned short* __restrict__ B1, size_t ldB1,
    const unsigned short* __restrict__ B2, size_t ldB2, int rowbase,
    unsigned short* As, unsigned short* Bs, f32x4 acc[4][2]) {
  const int total = c1 + c2;
  auto issue = [&](int c, int buf) {
    unsigned short* a = As + buf * 16384;
    unsigned short* b = Bs + buf * 8192;
    if (c < c1) {
      stageA(A1, ldA1, c << 7, a);
      stageB(B1, ldB1, rowbase, c << 7, b);
    } else {
      int k0 = (c - c1) << 7;
      stageA(A2, ldA2, k0, a);
      stageB(B2, ldB2, rowbase, k0, b);
    }
  };
  issue(0, 0);
  issue(1, 1);  // total >= 8 always (min K1+K2 = 1024)
  for (int c = 0; c < total; ++c) {
    __builtin_amdgcn_sched_barrier(0);  // pin prior compute before barrier
    if (c + 1 < total)
      WAITCNT_VM12();  // oldest 12 (chunk c) retired; c+1 stays in flight
    else
      WAITCNT_VM0();
    __builtin_amdgcn_s_barrier();       // raw: no compiler vmcnt(0) drain
    if (c + 2 < total) issue(c + 2, (c + 2) % 3);
    __builtin_amdgcn_sched_barrier(0);  // pin ds_reads after barrier/DMA
    cchunk(As + (c % 3) * 16384, Bs + (c % 3) * 8192, acc);
  }
}

// ---- zr: z/r gates for all active layers at tick u. 112 blocks. ----
__global__ __launch_bounds__(256) void diag_zr(DiagP p, int u) {
  __shared__ unsigned short As[3 * 16384], Bs[3 * 8192];
  const int blk = blockIdx.x;
  const int l = (blk < 16) ? 0 : ((blk < 48) ? 1 : 2);
  const int nt = blk - ((l == 0) ? 0 : ((l == 1) ? 16 : 48));
  const int t = u - l;
  if (t < 0 || t >= 128) return;
  const int H = (l == 0) ? 512 : ((l == 1) ? 1024 : 2048);
  const int inl = (l == 0) ? 512 : ((l == 1) ? 512 : 1024);
  const int oldS = (u + 1) & 1;

  const unsigned short* A1 =
      (l == 0) ? p.xb + (size_t)t * 512 : p.hb[l - 1][oldS];
  const size_t ldA1 = (l == 0) ? (size_t)128 * 512 : (size_t)inl;

  f32x4 acc[4][2] = {};
  gemm_diag(A1, ldA1, inl >> 7, p.hb[l][oldS], (size_t)H, H >> 7, p.wihzr[l],
            (size_t)inl, p.whhzr[l], (size_t)H, nt * 64, As, Bs, acc);

  const int tid = threadIdx.x, wave = tid >> 6, lane = tid & 63;
  const int wg = wave >> 1, wc = wave & 1, quad = lane >> 4, l16 = lane & 15;
  const float* hfo = p.hf[l][oldS];
#pragma unroll
  for (int ni = 0; ni < 2; ++ni) {
    int colg = nt * 64 + wc * 32 + ni * 16 + l16;
    float bv = p.bias[l][colg];
    const bool isz = colg < H;  // uniform per block (64 | H)
    int j = isz ? colg : colg - H;
#pragma unroll
    for (int mi = 0; mi < 4; ++mi)
#pragma unroll
      for (int r = 0; r < 4; ++r) {
        int row = wg * 64 + mi * 16 + quad * 4 + r;
        float v = acc[mi][ni][r] + bv;
        float s = sigmoidf_(v);
        if (isz)
          p.zb[l][(size_t)row * H + j] = s;
        else
          p.rh[l][(size_t)row * H + j] = f2b(s * hfo[(size_t)row * H + j]);
      }
  }
}

// ---- n: n gate + h update + masked out accumulation. 56 blocks. ----
__global__ __launch_bounds__(256) void diag_n(DiagP p, int u) {
  __shared__ unsigned short As[3 * 16384], Bs[3 * 8192];
  const int blk = blockIdx.x;
  const int l = (blk < 8) ? 0 : ((blk < 24) ? 1 : 2);
  const int nt = blk - ((l == 0) ? 0 : ((l == 1) ? 8 : 24));
  const int t = u - l;
  if (t < 0 || t >= 128) return;
  const int H = (l == 0) ? 512 : ((l == 1) ? 1024 : 2048);
  const int inl = (l == 0) ? 512 : ((l == 1) ? 512 : 1024);
  const int outoff = (l == 0) ? 0 : ((l == 1) ? 512 : 1536);
  const int oldS = (u + 1) & 1, newS = u & 1;

  const unsigned short* A1 =
      (l == 0) ? p.xb + (size_t)t * 512 : p.hb[l - 1][oldS];
  const size_t ldA1 = (l == 0) ? (size_t)128 * 512 : (size_t)inl;

  f32x4 acc[4][2] = {};
  gemm_diag(A1, ldA1, inl >> 7, p.rh[l], (size_t)H, H >> 7, p.wihn[l],
            (size_t)inl, p.whhn[l], (size_t)H, nt * 64, As, Bs, acc);

  const int tid = threadIdx.x, wave = tid >> 6, lane = tid & 63;
  const int wg = wave >> 1, wc = wave & 1, quad = lane >> 4, l16 = lane & 15;
  const float* hfo = p.hf[l][oldS];
  float* hfn = p.hf[l][newS];
  unsigned short* hbn = p.hb[l][newS];
#pragma unroll
  for (int ni = 0; ni < 2; ++ni) {
    int colg = nt * 64 + wc * 32 + ni * 16 + l16;
    float bv = p.bias[l][2 * H + colg];
#pragma unroll
    for (int mi = 0; mi < 4; ++mi)
#pragma unroll
      for (int r = 0; r < 4; ++r) {
        int row = wg * 64 + mi * 16 + quad * 4 + r;
        float v = acc[mi][ni][r] + bv;
        float nv = tanhf_(v);
        size_t idx = (size_t)row * H + colg;
        float z = p.zb[l][idx];
        float hn = (1.0f - z) * nv + z * hfo[idx];
        hfn[idx] = hn;
        hbn[idx] = f2b(hn);
        p.out[(size_t)row * 3584 + outoff + colg] +=
            p.mask[row * 128 + t] * hn;
      }
  }
}

__global__ void cast_kernel(const float* __restrict__ src,
                            unsigned short* __restrict__ dst, int n) {
  int i = blockIdx.x * 256 + threadIdx.x;
  if (i < n) dst[i] = f2b(src[i]);
}

extern "C" void kernel_launch(void* const* d_in, const int* in_sizes, int n_in,
                              void* d_out, int out_size, void* d_ws,
                              size_t ws_size, hipStream_t stream) {
  const int B = 128, T = 128, I = 512;
  const int Hs[3] = {512, 1024, 2048};

  const float* x = (const float*)d_in[0];
  const float* mask = (const float*)d_in[1];
  const float* Wih[3] = {(const float*)d_in[2], (const float*)d_in[5],
                         (const float*)d_in[8]};
  const float* Whh[3] = {(const float*)d_in[3], (const float*)d_in[6],
                         (const float*)d_in[9]};
  const float* bias[3] = {(const float*)d_in[4], (const float*)d_in[7],
                          (const float*)d_in[10]};

  char* ws = (char*)d_ws;
  size_t off = 0;
  auto alloc = [&](size_t bytes) -> void* {
    void* p = ws + off;
    off = (off + bytes + 255) & ~(size_t)255;
    return p;
  };

  unsigned short* xb = (unsigned short*)alloc((size_t)B * T * I * 2);
  unsigned short *wihb[3], *whhb[3];
  for (int l = 0; l < 3; ++l) {
    int inl = (l == 0) ? I : Hs[l - 1];
    wihb[l] = (unsigned short*)alloc((size_t)3 * Hs[l] * inl * 2);
    whhb[l] = (unsigned short*)alloc((size_t)3 * Hs[l] * Hs[l] * 2);
  }
  size_t hstart = off;
  DiagP p;
  for (int l = 0; l < 3; ++l)
    for (int sl = 0; sl < 2; ++sl)
      p.hf[l][sl] = (float*)alloc((size_t)B * Hs[l] * 4);
  for (int l = 0; l < 3; ++l)
    for (int sl = 0; sl < 2; ++sl)
      p.hb[l][sl] = (unsigned short*)alloc((size_t)B * Hs[l] * 2);
  size_t hend = off;
  for (int l = 0; l < 3; ++l) p.zb[l] = (float*)alloc((size_t)B * Hs[l] * 4);
  for (int l = 0; l < 3; ++l)
    p.rh[l] = (unsigned short*)alloc((size_t)B * Hs[l] * 2);
  (void)ws_size;

  p.xb = xb;
  for (int l = 0; l < 3; ++l) {
    int inl = (l == 0) ? I : Hs[l - 1];
    p.wihzr[l] = wihb[l];
    p.wihn[l] = wihb[l] + (size_t)2 * Hs[l] * inl;
    p.whhzr[l] = whhb[l];
    p.whhn[l] = whhb[l] + (size_t)2 * Hs[l] * Hs[l];
    p.bias[l] = bias[l];
  }
  p.mask = mask;
  p.out = (float*)d_out;

  auto cast = [&](const float* s, unsigned short* d, int n) {
    cast_kernel<<<(n + 255) / 256, 256, 0, stream>>>(s, d, n);
  };
  cast(x, xb, B * T * I);
  for (int l = 0; l < 3; ++l) {
    int inl = (l == 0) ? I : Hs[l - 1];
    cast(Wih[l], wihb[l], 3 * Hs[l] * inl);
    cast(Whh[l], whhb[l], 3 * Hs[l] * Hs[l]);
  }
  hipMemsetAsync(ws + hstart, 0, hend - hstart, stream);
  hipMemsetAsync(d_out, 0, (size_t)out_size * 4, stream);

  // ---- diagonal scan: tick u covers (l, t=u-l) ----
  for (int u = 0; u < T + 2; ++u) {
    diag_zr<<<112, 256, 0, stream>>>(p, u);
    diag_n<<<56, 256, 0, stream>>>(p, u);
  }
}